// Round 1
// baseline (187.087 us; speedup 1.0000x reference)
//
#include <hip/hip_runtime.h>
#include <hip/hip_bf16.h>

#define HW 9216          // 96*96
#define NPC 18432        // per-channel element count for BN
#define NELEM 1179648    // 2*64*96*96
#define PSTR 584         // prL pos stride (bf16): %8==0 (16B align), 292dw = +4 banks/pos
#define XSTR 72          // patch x stride (bf16): %8==0, 36dw = +4 banks/pos
#define PATCH_B 7776     // 3*18*72*2 bytes
#define PRL_O 18688      // 16*584*2 bytes (ONE o per block now)

typedef __attribute__((ext_vector_type(2))) float f32x2;
typedef __attribute__((ext_vector_type(4))) float f32x4v;
typedef __attribute__((ext_vector_type(8))) short short8v;   // 8 bf16 (4 VGPRs)

__device__ __forceinline__ f32x2 fma2(f32x2 a, f32x2 b, f32x2 c) {
#if __has_builtin(__builtin_elementwise_fma)
    return __builtin_elementwise_fma(a, b, c);
#else
    return f32x2{fmaf(a.x, b.x, c.x), fmaf(a.y, b.y, c.y)};
#endif
}
__device__ __forceinline__ float dot8v(f32x2 a0, f32x2 a1, f32x2 a2, f32x2 a3,
                                       f32x2 b0, f32x2 b1, f32x2 b2, f32x2 b3) {
    f32x2 acc = a0 * b0;
    acc = fma2(a1, b1, acc);
    acc = fma2(a2, b2, acc);
    acc = fma2(a3, b3, acc);
    return acc.x + acc.y;
}

template <int CTRL>
__device__ __forceinline__ float dpp_add(float x) {
    int y = __builtin_amdgcn_update_dpp(0, __float_as_int(x), CTRL, 0xF, 0xF, true);
    return x + __int_as_float(y);
}
template <int CTRL>
__device__ __forceinline__ f32x2 dpp_add2(f32x2 x) {   // packed pair: 2 movs + 1 pk add
    int ya = __builtin_amdgcn_update_dpp(0, __float_as_int(x.x), CTRL, 0xF, 0xF, true);
    int yb = __builtin_amdgcn_update_dpp(0, __float_as_int(x.y), CTRL, 0xF, 0xF, true);
    return x + f32x2{__int_as_float(ya), __int_as_float(yb)};
}
// sum over 16-lane group: xor1, xor2, half_mirror (8), row_mirror (16)
__device__ __forceinline__ float red16(float x) {
    x = dpp_add<0xB1>(x);    // quad_perm [1,0,3,2]
    x = dpp_add<0x4E>(x);    // quad_perm [2,3,0,1]
    x = dpp_add<0x141>(x);   // row_half_mirror
    x = dpp_add<0x140>(x);   // row_mirror
    return x;
}
__device__ __forceinline__ f32x2 red16_2(f32x2 x) {
    x = dpp_add2<0xB1>(x);
    x = dpp_add2<0x4E>(x);
    x = dpp_add2<0x141>(x);
    x = dpp_add2<0x140>(x);
    return x;
}

__device__ __forceinline__ int detect_is32(const unsigned short* __restrict__ w1u) {
    int lane = threadIdx.x & 63;
    int bad = 0;
    #pragma unroll
    for (int i = 0; i < 16; ++i) {
        unsigned short u = (unsigned short)(w1u[lane + i * 64] & 0x7FFF);
        bad |= (u >= 0x42C8);   // bf16 |v| >= 100 or NaN/Inf
    }
    return (__ballot(bad) != 0ULL) ? 1 : 0;
}

__device__ __forceinline__ float load_in(const void* p, int idx, int is32) {
    return is32 ? ((const float*)p)[idx]
                : __bfloat162float(((const __hip_bfloat16*)p)[idx]);
}

__device__ __forceinline__ float lo16(unsigned v) { return __int_as_float((int)(v << 16)); }
__device__ __forceinline__ float hi16(unsigned v) { return __int_as_float((int)(v & 0xFFFF0000u)); }
__device__ __forceinline__ unsigned pk2bf(float a, float b) {
    __hip_bfloat162 h = __float22bfloat162_rn(float2{a, b});
    return *(unsigned*)&h;
}

// ---------------------------------------------------------------------------
// prep: 0..575 x-transpose to bf16 [b][y][x][c]; 576..719 MFMA B-fragment
// tables; 720 zero BN-stat accumulators.
// ---------------------------------------------------------------------------
__launch_bounds__(256)
__global__ void prep_kernel(const void* __restrict__ x,
                            const void* __restrict__ w1, const void* __restrict__ w2,
                            __hip_bfloat16* __restrict__ xt,
                            __hip_bfloat16* __restrict__ Bfr1,
                            __hip_bfloat16* __restrict__ Bfr2,
                            float* __restrict__ statz) {
    __shared__ float tile[64 * 33];
    const int bid = blockIdx.x;
    if (bid < 576) {
        const int is32 = detect_is32((const unsigned short*)w1);
        int xb = bid % 3, y = (bid / 3) % 96, b = bid / 288;
        int x0 = xb * 32;
        for (int e = threadIdx.x; e < 2048; e += 256) {
            int xl = e & 31, c = e >> 5;
            tile[c * 33 + xl] = load_in(x, ((b * 64 + c) * 96 + y) * 96 + x0 + xl, is32);
        }
        __syncthreads();
        for (int f = threadIdx.x; f < 1024; f += 256) {
            int c2 = f & 31, xl = f >> 5;
            float a = tile[(2 * c2) * 33 + xl];
            float c = tile[(2 * c2 + 1) * 33 + xl];
            *(unsigned*)&xt[((b * 96 + y) * 96 + x0 + xl) * 64 + 2 * c2] = pk2bf(a, c);
        }
    } else if (bid < 720) {
        const int is32 = detect_is32((const unsigned short*)w1);
        int t = (bid - 576) * 256 + threadIdx.x;   // 0..36863
        int layer = t / 18432;
        int r = t - layer * 18432;
        int lane = r & 63;
        int fi = r >> 6;                 // 0..287 = ((o*9+k)*2+g)*2+h
        int h = fi & 1, g = (fi >> 1) & 1;
        int kq = fi >> 2;
        int k = kq % 9, o = kq / 9;
        int dy = k / 3, dx = k % 3;
        int quad = lane >> 4, colhi = (lane >> 3) & 1, m = lane & 7;
        int act = (quad == 2 * h + colhi);
        int i = g * 4 + 2 * h + colhi;
        const void* w = layer ? w2 : w1;
        __hip_bfloat16* dst = layer ? Bfr2 : Bfr1;
        #pragma unroll
        for (int j = 0; j < 8; ++j) {
            float v = act ? load_in(w, ((((o * 8 + i) * 3 + dy) * 3 + dx) * 8 + j) * 8 + m, is32)
                          : 0.f;
            dst[(fi * 64 + lane) * 8 + j] = __float2bfloat16(v);
        }
    } else {
        for (int e = threadIdx.x; e < 2048; e += 256) statz[e] = 0.f;
    }
}

// ---------------------------------------------------------------------------
// Fused capsule conv (MFMA) + routing + BN-stat partials.
// R17: ONE o per block (grid x = 6 xtiles x 8 o). LDS = patch + 1 prior buf
// = 26.5 KB -> 4 blocks/CU (was 3, LDS-capped). Routing unit widened to 16
// lanes (8 i x 2 k-halves, k split even/odd with a zero 5th slot on the odd
// half) so per-lane live state is 40 floats -> stays in registers, priors
// read from LDS exactly once (was: compiler remat/reload at VGPR=68).
// Phase 1: 4 waves = (g,h), 9 operand-swapped MFMAs each; lane's 4 acc regs
// = 4 consecutive m of one (pos,i') => one ds_write_b64 per MFMA.
// ---------------------------------------------------------------------------
__launch_bounds__(256, 4)
__global__ void caps_kernel(const __hip_bfloat16* __restrict__ in,  // [b][y][x][64] bf16
                            const float* __restrict__ statPrev,     // BN1 raw stats (layer2)
                            const void* __restrict__ gamma, const void* __restrict__ beta,
                            const void* __restrict__ wdt,           // w1, dtype probe
                            const __hip_bfloat16* __restrict__ Bfr,
                            __hip_bfloat16* __restrict__ yout,      // [b][y][x][64] bf16
                            float* __restrict__ statL,              // [8 copies][128]
                            int layer1) {
    __shared__ __align__(16) unsigned char smem[PATCH_B + PRL_O];
    __hip_bfloat16* patchH = (__hip_bfloat16*)smem;             // [q=row*18+xo][c] stride XSTR
    __hip_bfloat16* prH    = (__hip_bfloat16*)(smem + PATCH_B); // [pos]*PSTR + (i*9+k)*8+m
    float* omF = (float*)smem;                // 512 B, aliases patch (dead in epilogue)
    float* scL = (float*)(smem + PATCH_B);    // 256 B, aliases prH head (staging only)
    float* shL = scL + 64;

    const int gx = blockIdx.x;   // 0..47: o fastest (blocks sharing a patch stay L2-close)
    const int o  = gx & 7;
    const int x0 = (gx >> 3) * 16;
    const int y  = blockIdx.y;
    const int b  = blockIdx.z;
    const int tid = threadIdx.x;

    // ---- inline BN1 params (layer 2 only) ----
    if (!layer1) {
        if (tid < 64) {
            const int is32 = detect_is32((const unsigned short*)wdt);
            int c = tid;
            float s = 0.f, ss = 0.f;
            #pragma unroll
            for (int cp = 0; cp < 8; ++cp) {
                s  += statPrev[cp * 128 + c];
                ss += statPrev[cp * 128 + 64 + c];
            }
            float mean = s * (1.f / (float)NPC);
            float var  = fmaxf(ss * (1.f / (float)NPC) - mean * mean, 0.f);
            float inv  = rsqrtf(var + 1e-5f);
            float g = load_in(gamma, c, is32) * inv;
            scL[c] = g;
            shL[c] = load_in(beta, c, is32) - mean * g;
        }
        __syncthreads();
    }

    // ---- stage patch: rows y-1..y+1, cols x0-1..x0+16, 64 ch bf16 ----
    for (int e = tid; e < 864; e += 256) {
        int c4 = e & 15;             // 4-channel group
        int q  = e >> 4;             // 0..53 = row*18 + xo
        int xo = q % 18, row = q / 18;
        int yy = y + row - 1, xx = x0 + xo - 1;
        uint2 v = {0u, 0u};
        if (yy >= 0 && yy < 96 && xx >= 0 && xx < 96) {
            v = *(const uint2*)&in[((b * 96 + yy) * 96 + xx) * 64 + c4 * 4];
            if (!layer1) {
                int c = c4 * 4;
                float f0 = lo16(v.x) * scL[c]     + shL[c];
                float f1 = hi16(v.x) * scL[c + 1] + shL[c + 1];
                float f2 = lo16(v.y) * scL[c + 2] + shL[c + 2];
                float f3 = hi16(v.y) * scL[c + 3] + shL[c + 3];
                v.x = pk2bf(f0, f1);
                v.y = pk2bf(f2, f3);
            }
        }
        *(uint2*)&patchH[q * XSTR + c4 * 4] = v;
    }
    __syncthreads();

    const int lane = tid & 63;
    const int wv   = tid >> 6;       // wave 0..3 = (h<<1 | g)

    // ================= Phase 1: priors via operand-swapped MFMA =============
    {
        const int g = wv & 1;        // i-group
        const int h = wv >> 1;       // h-pair
        const int pos16 = lane & 15;         // B col = position
        const int quad  = lane >> 4;
        const int mbase = (quad & 1) * 4;    // D rows quad*4+r => m = mbase+r
        const int ihl   = quad >> 1;         // i'-local (within the h pair)
        const int iw    = g * 4 + 2 * h + ihl;
        #pragma unroll
        for (int k = 0; k < 9; ++k) {
            const int dy = k / 3, dx = k % 3;
            short8v a = *(const short8v*)&patchH[(dy * 18 + dx + pos16) * XSTR + g * 32 + quad * 8];
            short8v bf = *(const short8v*)&Bfr[((((o * 9 + k) * 2 + g) * 2 + h) * 64 + lane) * 8];
            // A = weight fragment, B = patch fragment (mirrored lane maps)
            f32x4v d = __builtin_amdgcn_mfma_f32_16x16x32_bf16(bf, a, (f32x4v){0.f, 0.f, 0.f, 0.f}, 0, 0, 0);
            uint2 pk;
            pk.x = pk2bf(d[0], d[1]);
            pk.y = pk2bf(d[2], d[3]);
            *(uint2*)&prH[pos16 * PSTR + (iw * 9 + k) * 8 + mbase] = pk;
        }
    }
    __syncthreads();

    // ============ Phase 2: routing, unit = pos (16 lanes: 8 i x 2 k-halves) =
    const int pos = tid >> 4;        // 0..15
    const int i   = tid & 7;
    const int kh  = (tid >> 3) & 1;  // k parity: kh=0 -> k=0,2,4,6,8 ; kh=1 -> k=1,3,5,7,(pad)
    const __hip_bfloat16* pb = &prH[pos * PSTR + i * 72];

    uint4 u[5];
    #pragma unroll
    for (int t = 0; t < 4; ++t) u[t] = *(const uint4*)(pb + (kh + 2 * t) * 8);
    u[4] = *(const uint4*)(pb + 8 * 8);          // k=8 slot (valid memory for all lanes)
    if (kh) { u[4].x = 0u; u[4].y = 0u; u[4].z = 0u; u[4].w = 0u; }  // pad slot -> zero priors

    f32x2 fr[20];
    float n1[5];
    #pragma unroll
    for (int t = 0; t < 5; ++t) {
        fr[4 * t + 0] = f32x2{lo16(u[t].x), hi16(u[t].x)};
        fr[4 * t + 1] = f32x2{lo16(u[t].y), hi16(u[t].y)};
        fr[4 * t + 2] = f32x2{lo16(u[t].z), hi16(u[t].z)};
        fr[4 * t + 3] = f32x2{lo16(u[t].w), hi16(u[t].w)};
    }

    // om init = mean over all 72 j: sum over t in-lane, then DPP-sum over 16 lanes.
    f32x2 om2[4];
    {
        f32x2 s2[4] = {f32x2{0.f, 0.f}, f32x2{0.f, 0.f}, f32x2{0.f, 0.f}, f32x2{0.f, 0.f}};
        #pragma unroll
        for (int t = 0; t < 5; ++t) {
            s2[0] += fr[4 * t + 0];
            s2[1] += fr[4 * t + 1];
            s2[2] += fr[4 * t + 2];
            s2[3] += fr[4 * t + 3];
        }
        #pragma unroll
        for (int q = 0; q < 4; ++q) {
            f32x2 tt = red16_2(s2[q]);
            om2[q] = tt * f32x2{1.f / 72.f, 1.f / 72.f};
        }
    }
    float n2 = dot8v(om2[0], om2[1], om2[2], om2[3], om2[0], om2[1], om2[2], om2[3]);

    #pragma unroll
    for (int it = 0; it < 3; ++it) {
        // pad slot (kh=1, t=4): d=0, n1=0 -> e=exp(0)=1; cancel via se init -1.
        float se = kh ? -1.f : 0.f;
        f32x2 acc2[4] = {f32x2{0.f, 0.f}, f32x2{0.f, 0.f}, f32x2{0.f, 0.f}, f32x2{0.f, 0.f}};
        #pragma unroll
        for (int t = 0; t < 5; ++t) {
            if (it == 0)
                n1[t] = dot8v(fr[4 * t], fr[4 * t + 1], fr[4 * t + 2], fr[4 * t + 3],
                              fr[4 * t], fr[4 * t + 1], fr[4 * t + 2], fr[4 * t + 3]);
            float d = dot8v(fr[4 * t], fr[4 * t + 1], fr[4 * t + 2], fr[4 * t + 3],
                            om2[0], om2[1], om2[2], om2[3]);
            float denom = fmaxf(n1[t] + n2 - d, 1e-8f);
            float e = __expf(d * __builtin_amdgcn_rcpf(denom));
            se += e;
            f32x2 ev{e, e};
            acc2[0] = fma2(ev, fr[4 * t + 0], acc2[0]);
            acc2[1] = fma2(ev, fr[4 * t + 1], acc2[1]);
            acc2[2] = fma2(ev, fr[4 * t + 2], acc2[2]);
            acc2[3] = fma2(ev, fr[4 * t + 3], acc2[3]);
        }
        se = red16(se);
        #pragma unroll
        for (int q = 0; q < 4; ++q) acc2[q] = red16_2(acc2[q]);
        float inv = __builtin_amdgcn_rcpf(se);
        f32x2 iv{inv, inv};
        #pragma unroll
        for (int q = 0; q < 4; ++q) om2[q] = acc2[q] * iv;
        n2 = dot8v(om2[0], om2[1], om2[2], om2[3], om2[0], om2[1], om2[2], om2[3]);
    }

    if ((tid & 15) == 0) {
        uint4 pk;
        pk.x = pk2bf(om2[0].x, om2[0].y);
        pk.y = pk2bf(om2[1].x, om2[1].y);
        pk.z = pk2bf(om2[2].x, om2[2].y);
        pk.w = pk2bf(om2[3].x, om2[3].y);
        *(uint4*)&yout[((b * 96 + y) * 96 + x0 + pos) * 64 + o * 8] = pk;
        // park f32 finals for BN stats (patch region, dead)
        float4 o0 = {om2[0].x, om2[0].y, om2[1].x, om2[1].y};
        float4 o1 = {om2[2].x, om2[2].y, om2[3].x, om2[3].y};
        *(float4*)&omF[pos * 8] = o0;
        *(float4*)&omF[pos * 8 + 4] = o1;
    }
    __syncthreads();

    // ---- BN stat partials: this block's 8 channels, sum over 16 positions ----
    if (tid < 16) {
        int m = tid & 7, sel = tid >> 3;
        float v = 0.f;
        #pragma unroll
        for (int pp = 0; pp < 16; ++pp) {
            float t = omF[pp * 8 + m];
            v += sel ? t * t : t;
        }
        int cp = (blockIdx.x + blockIdx.y * 3 + blockIdx.z) & 7;
        atomicAdd(&statL[cp * 128 + sel * 64 + o * 8 + m], v);
    }
}

// ---------------------------------------------------------------------------
// Final: out[b][c][y][x] = x + bn2(y2); bn2 params computed inline per block.
// ---------------------------------------------------------------------------
__launch_bounds__(256)
__global__ void final_kernel(const void* __restrict__ xin,
                             const __hip_bfloat16* __restrict__ yt2,
                             const float* __restrict__ statL,
                             const void* __restrict__ gamma, const void* __restrict__ beta,
                             const void* __restrict__ w1,
                             void* __restrict__ outp) {
    __shared__ float tile[64 * 33];
    __shared__ float scL[64], shL[64];
    const int is32 = detect_is32((const unsigned short*)w1);
    if (threadIdx.x < 64) {
        int c = threadIdx.x;
        float s = 0.f, ss = 0.f;
        #pragma unroll
        for (int cp = 0; cp < 8; ++cp) {
            s  += statL[cp * 128 + c];
            ss += statL[cp * 128 + 64 + c];
        }
        float mean = s * (1.f / (float)NPC);
        float var  = fmaxf(ss * (1.f / (float)NPC) - mean * mean, 0.f);
        float inv  = rsqrtf(var + 1e-5f);
        float g = load_in(gamma, c, is32) * inv;
        scL[c] = g;
        shL[c] = load_in(beta, c, is32) - mean * g;
    }
    __syncthreads();

    int x0 = blockIdx.x * 32, y = blockIdx.y, b = blockIdx.z;
    for (int e = threadIdx.x; e < 1024; e += 256) {
        int c2 = e & 31, xl = e >> 5;
        unsigned v = *(const unsigned*)&yt2[((b * 96 + y) * 96 + x0 + xl) * 64 + c2 * 2];
        int c = c2 * 2;
        tile[c * 33 + xl]       = lo16(v) * scL[c]     + shL[c];
        tile[(c + 1) * 33 + xl] = hi16(v) * scL[c + 1] + shL[c + 1];
    }
    __syncthreads();
    for (int f = threadIdx.x; f < 2048; f += 256) {
        int xl = f & 31, c = f >> 5;
        int idx = ((b * 64 + c) * 96 + y) * 96 + x0 + xl;
        float v = load_in(xin, idx, is32) + tile[c * 33 + xl];
        if (is32) ((float*)outp)[idx] = v;
        else      ((__hip_bfloat16*)outp)[idx] = __float2bfloat16(v);
    }
}

// ---------------------------------------------------------------------------
extern "C" void kernel_launch(void* const* d_in, const int* in_sizes, int n_in,
                              void* d_out, int out_size, void* d_ws, size_t ws_size,
                              hipStream_t stream) {
    const void* x  = d_in[0];
    const void* w1 = d_in[1];
    const void* g1 = d_in[2];
    const void* b1 = d_in[3];
    const void* w2 = d_in[4];
    const void* g2 = d_in[5];
    const void* b2 = d_in[6];

    __hip_bfloat16* bufA = (__hip_bfloat16*)d_ws;   // xt / yt2 (bf16, aliased)
    __hip_bfloat16* bufB = bufA + NELEM;            // yt1 (bf16)
    __hip_bfloat16* Bfr1 = bufB + NELEM;            // 147456 bf16
    __hip_bfloat16* Bfr2 = Bfr1 + 147456;           // 147456 bf16
    float* statz = (float*)(Bfr2 + 147456);         // 2048 f32
    float* statL1 = statz;
    float* statL2 = statz + 1024;

    prep_kernel<<<721, 256, 0, stream>>>(x, w1, w2, bufA, Bfr1, Bfr2, statz);

    dim3 cgrid(48, 96, 2);   // (8 o x 6 xtiles of 16), rows, batch
    caps_kernel<<<cgrid, 256, 0, stream>>>(bufA, nullptr, nullptr, nullptr, w1,
                                           Bfr1, bufB, statL1, 1);
    caps_kernel<<<cgrid, 256, 0, stream>>>(bufB, statL1, g1, b1, w1,
                                           Bfr2, bufA, statL2, 0);
    final_kernel<<<dim3(3, 96, 2), 256, 0, stream>>>(x, bufA, statL2, g2, b2, w1, d_out);
}

// Round 2
// 179.883 us; speedup vs baseline: 1.0400x; 1.0400x over previous
//
#include <hip/hip_runtime.h>
#include <hip/hip_bf16.h>

#define HW 9216          // 96*96
#define NPC 18432        // per-channel element count for BN
#define NELEM 1179648    // 2*64*96*96
#define PSTR 584         // prL pos stride (bf16): %8==0 (16B align), 292dw = +4 banks/pos
#define XSTR 72          // patch x stride (bf16): %8==0, 36dw = +4 banks/pos
#define PATCH_B 7776     // 3*18*72*2 bytes
#define PRL_O 18688      // 16*584*2 bytes (per o)

typedef __attribute__((ext_vector_type(2))) float f32x2;
typedef __attribute__((ext_vector_type(4))) float f32x4v;
typedef __attribute__((ext_vector_type(8))) short short8v;   // 8 bf16 (4 VGPRs)

__device__ __forceinline__ f32x2 fma2(f32x2 a, f32x2 b, f32x2 c) {
#if __has_builtin(__builtin_elementwise_fma)
    return __builtin_elementwise_fma(a, b, c);
#else
    return f32x2{fmaf(a.x, b.x, c.x), fmaf(a.y, b.y, c.y)};
#endif
}
__device__ __forceinline__ float dot8v(f32x2 a0, f32x2 a1, f32x2 a2, f32x2 a3,
                                       f32x2 b0, f32x2 b1, f32x2 b2, f32x2 b3) {
    f32x2 acc = a0 * b0;
    acc = fma2(a1, b1, acc);
    acc = fma2(a2, b2, acc);
    acc = fma2(a3, b3, acc);
    return acc.x + acc.y;
}

// anti-remat pin: opaque def the compiler cannot rematerialize through.
// Keeps the unpacked f32 priors LIVE in VGPRs instead of re-unpacking the
// packed bf16 words at every use (R16/R17 post-mortem: VGPR=40..68 with
// ~2.5-3x VALU inflation from per-use remat of the lo16/hi16 chains).
__device__ __forceinline__ void keep2(f32x2 &v) {
    asm volatile("" : "+v"(v));
}
__device__ __forceinline__ void keepf(float &x) {
    asm volatile("" : "+v"(x));
}

template <int CTRL>
__device__ __forceinline__ float dpp_add(float x) {
    int y = __builtin_amdgcn_update_dpp(0, __float_as_int(x), CTRL, 0xF, 0xF, true);
    return x + __int_as_float(y);
}
template <int CTRL>
__device__ __forceinline__ f32x2 dpp_add2(f32x2 x) {   // packed pair: 2 movs + 1 pk add
    int ya = __builtin_amdgcn_update_dpp(0, __float_as_int(x.x), CTRL, 0xF, 0xF, true);
    int yb = __builtin_amdgcn_update_dpp(0, __float_as_int(x.y), CTRL, 0xF, 0xF, true);
    return x + f32x2{__int_as_float(ya), __int_as_float(yb)};
}
__device__ __forceinline__ float red_lo(float x) {   // sum over lane xor 1,2,4
    x = dpp_add<0xB1>(x);    // quad_perm [1,0,3,2]
    x = dpp_add<0x4E>(x);    // quad_perm [2,3,0,1]
    x = dpp_add<0x141>(x);   // row_half_mirror
    return x;
}
__device__ __forceinline__ f32x2 red_lo2(f32x2 x) {
    x = dpp_add2<0xB1>(x);
    x = dpp_add2<0x4E>(x);
    x = dpp_add2<0x141>(x);
    return x;
}

__device__ __forceinline__ int detect_is32(const unsigned short* __restrict__ w1u) {
    int lane = threadIdx.x & 63;
    int bad = 0;
    #pragma unroll
    for (int i = 0; i < 16; ++i) {
        unsigned short u = (unsigned short)(w1u[lane + i * 64] & 0x7FFF);
        bad |= (u >= 0x42C8);   // bf16 |v| >= 100 or NaN/Inf
    }
    return (__ballot(bad) != 0ULL) ? 1 : 0;
}

__device__ __forceinline__ float load_in(const void* p, int idx, int is32) {
    return is32 ? ((const float*)p)[idx]
                : __bfloat162float(((const __hip_bfloat16*)p)[idx]);
}

__device__ __forceinline__ float lo16(unsigned v) { return __int_as_float((int)(v << 16)); }
__device__ __forceinline__ float hi16(unsigned v) { return __int_as_float((int)(v & 0xFFFF0000u)); }
__device__ __forceinline__ unsigned pk2bf(float a, float b) {
    __hip_bfloat162 h = __float22bfloat162_rn(float2{a, b});
    return *(unsigned*)&h;
}

// ---------------------------------------------------------------------------
// prep: 0..575 x-transpose to bf16 [b][y][x][c]; 576..719 MFMA B-fragment
// tables; 720 zero BN-stat accumulators.
// ---------------------------------------------------------------------------
__launch_bounds__(256)
__global__ void prep_kernel(const void* __restrict__ x,
                            const void* __restrict__ w1, const void* __restrict__ w2,
                            __hip_bfloat16* __restrict__ xt,
                            __hip_bfloat16* __restrict__ Bfr1,
                            __hip_bfloat16* __restrict__ Bfr2,
                            float* __restrict__ statz) {
    __shared__ float tile[64 * 33];
    const int bid = blockIdx.x;
    if (bid < 576) {
        const int is32 = detect_is32((const unsigned short*)w1);
        int xb = bid % 3, y = (bid / 3) % 96, b = bid / 288;
        int x0 = xb * 32;
        for (int e = threadIdx.x; e < 2048; e += 256) {
            int xl = e & 31, c = e >> 5;
            tile[c * 33 + xl] = load_in(x, ((b * 64 + c) * 96 + y) * 96 + x0 + xl, is32);
        }
        __syncthreads();
        for (int f = threadIdx.x; f < 1024; f += 256) {
            int c2 = f & 31, xl = f >> 5;
            float a = tile[(2 * c2) * 33 + xl];
            float c = tile[(2 * c2 + 1) * 33 + xl];
            *(unsigned*)&xt[((b * 96 + y) * 96 + x0 + xl) * 64 + 2 * c2] = pk2bf(a, c);
        }
    } else if (bid < 720) {
        const int is32 = detect_is32((const unsigned short*)w1);
        int t = (bid - 576) * 256 + threadIdx.x;   // 0..36863
        int layer = t / 18432;
        int r = t - layer * 18432;
        int lane = r & 63;
        int fi = r >> 6;                 // 0..287 = ((o*9+k)*2+g)*2+h
        int h = fi & 1, g = (fi >> 1) & 1;
        int kq = fi >> 2;
        int k = kq % 9, o = kq / 9;
        int dy = k / 3, dx = k % 3;
        int quad = lane >> 4, colhi = (lane >> 3) & 1, m = lane & 7;
        int act = (quad == 2 * h + colhi);
        int i = g * 4 + 2 * h + colhi;
        const void* w = layer ? w2 : w1;
        __hip_bfloat16* dst = layer ? Bfr2 : Bfr1;
        #pragma unroll
        for (int j = 0; j < 8; ++j) {
            float v = act ? load_in(w, ((((o * 8 + i) * 3 + dy) * 3 + dx) * 8 + j) * 8 + m, is32)
                          : 0.f;
            dst[(fi * 64 + lane) * 8 + j] = __float2bfloat16(v);
        }
    } else {
        for (int e = threadIdx.x; e < 2048; e += 256) statz[e] = 0.f;
    }
}

// ---------------------------------------------------------------------------
// Fused capsule conv (MFMA) + routing + BN-stat partials.  (R16 structure +
// anti-remat pins.)
// Block = 256 threads = 4 waves; tile = 16 x-positions x TWO o.
// Wave w = (o2 = w>>1, g = w&1). Patch staged ONCE for both o's (bf16 uint2).
// Phase 1: OPERAND-SWAPPED MFMA — D = Bfr(A-role) x patch(B-role), so each
//   lane's 4 acc regs are 4 consecutive m of one (pos,i') => one
//   ds_write_b64 per MFMA.
// Phase 2: 32 routing units = 256 threads; m in-lane, DPP reductions.
//   Priors unpacked ONCE to f32 and pinned live via empty inline asm
//   (compiler otherwise remats the bf16 unpack at every use: ~3x VALU).
// ---------------------------------------------------------------------------
__launch_bounds__(256, 3)
__global__ void caps_kernel(const __hip_bfloat16* __restrict__ in,  // [b][y][x][64] bf16
                            const float* __restrict__ statPrev,     // BN1 raw stats (layer2)
                            const void* __restrict__ gamma, const void* __restrict__ beta,
                            const void* __restrict__ wdt,           // w1, dtype probe
                            const __hip_bfloat16* __restrict__ Bfr,
                            __hip_bfloat16* __restrict__ yout,      // [b][y][x][64] bf16
                            float* __restrict__ statL,              // [8 copies][128]
                            int layer1) {
    __shared__ __align__(16) unsigned char smem[PATCH_B + 2 * PRL_O];
    __hip_bfloat16* patchH = (__hip_bfloat16*)smem;             // [q=row*18+xo][c] stride XSTR
    __hip_bfloat16* prH    = (__hip_bfloat16*)(smem + PATCH_B); // [o2]*9344 + [pos]*PSTR + (i*9+k)*8+m
    float* omF = (float*)smem;                // 1 KB, aliases patch (dead in epilogue)
    float* scL = (float*)(smem + PATCH_B);    // 256 B, aliases prL head (staging only)
    float* shL = scL + 64;

    const int gx    = blockIdx.x;    // 0..23
    const int opair = gx & 3;
    const int x0    = (gx >> 2) * 16;
    const int y  = blockIdx.y;
    const int b  = blockIdx.z;
    const int tid = threadIdx.x;

    // ---- inline BN1 params (layer 2 only) ----
    if (!layer1) {
        if (tid < 64) {
            const int is32 = detect_is32((const unsigned short*)wdt);
            int c = tid;
            float s = 0.f, ss = 0.f;
            #pragma unroll
            for (int cp = 0; cp < 8; ++cp) {
                s  += statPrev[cp * 128 + c];
                ss += statPrev[cp * 128 + 64 + c];
            }
            float mean = s * (1.f / (float)NPC);
            float var  = fmaxf(ss * (1.f / (float)NPC) - mean * mean, 0.f);
            float inv  = rsqrtf(var + 1e-5f);
            float g = load_in(gamma, c, is32) * inv;
            scL[c] = g;
            shL[c] = load_in(beta, c, is32) - mean * g;
        }
        __syncthreads();
    }

    // ---- stage patch: rows y-1..y+1, cols x0-1..x0+16, 64 ch bf16 ----
    for (int e = tid; e < 864; e += 256) {
        int c4 = e & 15;             // 4-channel group
        int q  = e >> 4;             // 0..53 = row*18 + xo
        int xo = q % 18, row = q / 18;
        int yy = y + row - 1, xx = x0 + xo - 1;
        uint2 v = {0u, 0u};
        if (yy >= 0 && yy < 96 && xx >= 0 && xx < 96) {
            v = *(const uint2*)&in[((b * 96 + yy) * 96 + xx) * 64 + c4 * 4];
            if (!layer1) {
                int c = c4 * 4;
                float f0 = lo16(v.x) * scL[c]     + shL[c];
                float f1 = hi16(v.x) * scL[c + 1] + shL[c + 1];
                float f2 = lo16(v.y) * scL[c + 2] + shL[c + 2];
                float f3 = hi16(v.y) * scL[c + 3] + shL[c + 3];
                v.x = pk2bf(f0, f1);
                v.y = pk2bf(f2, f3);
            }
        }
        *(uint2*)&patchH[q * XSTR + c4 * 4] = v;
    }
    __syncthreads();

    const int lane = tid & 63;
    const int wv   = tid >> 6;       // wave 0..3
    const int o2w  = wv >> 1;        // which o of the pair
    const int g    = wv & 1;         // i-group

    // ================= Phase 1: priors via operand-swapped MFMA =============
    {
        const int o     = opair * 2 + o2w;
        const int pos16 = lane & 15;         // B col = position
        const int quad  = lane >> 4;
        const int mbase = (quad & 1) * 4;    // D rows quad*4+r => m = mbase+r
        const int ihl   = quad >> 1;         // i'-local (within the h pair)
        __hip_bfloat16* prBase = prH + o2w * 9344;
        #pragma unroll
        for (int k = 0; k < 9; ++k) {
            const int dy = k / 3, dx = k % 3;
            short8v a = *(const short8v*)&patchH[(dy * 18 + dx + pos16) * XSTR + g * 32 + quad * 8];
            #pragma unroll
            for (int h = 0; h < 2; ++h) {
                short8v bf = *(const short8v*)&Bfr[((((o * 9 + k) * 2 + g) * 2 + h) * 64 + lane) * 8];
                // A = weight fragment, B = patch fragment (mirrored lane maps)
                f32x4v d = __builtin_amdgcn_mfma_f32_16x16x32_bf16(bf, a, (f32x4v){0.f, 0.f, 0.f, 0.f}, 0, 0, 0);
                const int iw = g * 4 + 2 * h + ihl;
                uint2 pk;
                pk.x = pk2bf(d[0], d[1]);
                pk.y = pk2bf(d[2], d[3]);
                *(uint2*)&prBase[pos16 * PSTR + (iw * 9 + k) * 8 + mbase] = pk;
            }
        }
    }
    __syncthreads();

    // ============ Phase 2: routing (unit = (o2,pos), lane-group = unit) ======
    const int unit = tid >> 3;       // 0..31
    const int o2   = unit >> 4;
    const int pos  = unit & 15;
    const int i    = tid & 7;
    const __hip_bfloat16* pb = &prH[o2 * 9344 + pos * PSTR + i * 72];

    uint4 u[9];
    #pragma unroll
    for (int k = 0; k < 9; ++k) u[k] = *(const uint4*)(pb + k * 8);

    f32x2 fr[36];
    #pragma unroll
    for (int k = 0; k < 9; ++k) {
        fr[4 * k + 0] = f32x2{lo16(u[k].x), hi16(u[k].x)};
        fr[4 * k + 1] = f32x2{lo16(u[k].y), hi16(u[k].y)};
        fr[4 * k + 2] = f32x2{lo16(u[k].z), hi16(u[k].z)};
        fr[4 * k + 3] = f32x2{lo16(u[k].w), hi16(u[k].w)};
    }
    // pin the unpacked priors live: forbids per-use remat of the unpack chain
    #pragma unroll
    for (int q = 0; q < 36; ++q) keep2(fr[q]);

    // n1 once (loop-invariant), pinned too
    float n1[9];
    #pragma unroll
    for (int k = 0; k < 9; ++k) {
        n1[k] = dot8v(fr[4 * k], fr[4 * k + 1], fr[4 * k + 2], fr[4 * k + 3],
                      fr[4 * k], fr[4 * k + 1], fr[4 * k + 2], fr[4 * k + 3]);
        keepf(n1[k]);
    }

    // om init = mean over all 72 j: sum over k in-lane, then DPP-sum over i.
    f32x2 om2[4];
    {
        f32x2 s2[4] = {f32x2{0.f, 0.f}, f32x2{0.f, 0.f}, f32x2{0.f, 0.f}, f32x2{0.f, 0.f}};
        #pragma unroll
        for (int k = 0; k < 9; ++k) {
            s2[0] += fr[4 * k + 0];
            s2[1] += fr[4 * k + 1];
            s2[2] += fr[4 * k + 2];
            s2[3] += fr[4 * k + 3];
        }
        #pragma unroll
        for (int q = 0; q < 4; ++q) {
            f32x2 t = red_lo2(s2[q]);
            om2[q] = t * f32x2{1.f / 72.f, 1.f / 72.f};
        }
    }
    float n2 = dot8v(om2[0], om2[1], om2[2], om2[3], om2[0], om2[1], om2[2], om2[3]);

    #pragma unroll
    for (int it = 0; it < 3; ++it) {
        float se = 0.f;
        f32x2 acc2[4] = {f32x2{0.f, 0.f}, f32x2{0.f, 0.f}, f32x2{0.f, 0.f}, f32x2{0.f, 0.f}};
        #pragma unroll
        for (int k = 0; k < 9; ++k) {
            float d = dot8v(fr[4 * k], fr[4 * k + 1], fr[4 * k + 2], fr[4 * k + 3],
                            om2[0], om2[1], om2[2], om2[3]);
            float denom = fmaxf(n1[k] + n2 - d, 1e-8f);
            float e = __expf(d * __builtin_amdgcn_rcpf(denom));
            se += e;
            f32x2 ev{e, e};
            acc2[0] = fma2(ev, fr[4 * k + 0], acc2[0]);
            acc2[1] = fma2(ev, fr[4 * k + 1], acc2[1]);
            acc2[2] = fma2(ev, fr[4 * k + 2], acc2[2]);
            acc2[3] = fma2(ev, fr[4 * k + 3], acc2[3]);
        }
        se = red_lo(se);
        #pragma unroll
        for (int q = 0; q < 4; ++q) acc2[q] = red_lo2(acc2[q]);
        float inv = __builtin_amdgcn_rcpf(se);
        f32x2 iv{inv, inv};
        #pragma unroll
        for (int q = 0; q < 4; ++q) om2[q] = acc2[q] * iv;
        n2 = dot8v(om2[0], om2[1], om2[2], om2[3], om2[0], om2[1], om2[2], om2[3]);
    }

    if (i == 0) {
        const int o = opair * 2 + o2;
        uint4 pk;
        pk.x = pk2bf(om2[0].x, om2[0].y);
        pk.y = pk2bf(om2[1].x, om2[1].y);
        pk.z = pk2bf(om2[2].x, om2[2].y);
        pk.w = pk2bf(om2[3].x, om2[3].y);
        *(uint4*)&yout[((b * 96 + y) * 96 + x0 + pos) * 64 + o * 8] = pk;
        // park f32 finals for BN stats (patch region, dead)
        float4 o0 = {om2[0].x, om2[0].y, om2[1].x, om2[1].y};
        float4 o1 = {om2[2].x, om2[2].y, om2[3].x, om2[3].y};
        *(float4*)&omF[unit * 8] = o0;
        *(float4*)&omF[unit * 8 + 4] = o1;
    }
    __syncthreads();

    // ---- BN stat partials: this block's 16 channels, sum over 16 positions ----
    if (tid < 32) {
        int c16 = tid & 15, sel = tid >> 4;
        int oo2 = c16 >> 3, m = c16 & 7;
        float v = 0.f;
        #pragma unroll
        for (int pp = 0; pp < 16; ++pp) {
            float t = omF[(oo2 * 16 + pp) * 8 + m];
            v += sel ? t * t : t;
        }
        int cp = (blockIdx.x + blockIdx.y * 3 + blockIdx.z) & 7;
        atomicAdd(&statL[cp * 128 + sel * 64 + (opair * 2 + oo2) * 8 + m], v);
    }
}

// ---------------------------------------------------------------------------
// Final: out[b][c][y][x] = x + bn2(y2); bn2 params computed inline per block.
// ---------------------------------------------------------------------------
__launch_bounds__(256)
__global__ void final_kernel(const void* __restrict__ xin,
                             const __hip_bfloat16* __restrict__ yt2,
                             const float* __restrict__ statL,
                             const void* __restrict__ gamma, const void* __restrict__ beta,
                             const void* __restrict__ w1,
                             void* __restrict__ outp) {
    __shared__ float tile[64 * 33];
    __shared__ float scL[64], shL[64];
    const int is32 = detect_is32((const unsigned short*)w1);
    if (threadIdx.x < 64) {
        int c = threadIdx.x;
        float s = 0.f, ss = 0.f;
        #pragma unroll
        for (int cp = 0; cp < 8; ++cp) {
            s  += statL[cp * 128 + c];
            ss += statL[cp * 128 + 64 + c];
        }
        float mean = s * (1.f / (float)NPC);
        float var  = fmaxf(ss * (1.f / (float)NPC) - mean * mean, 0.f);
        float inv  = rsqrtf(var + 1e-5f);
        float g = load_in(gamma, c, is32) * inv;
        scL[c] = g;
        shL[c] = load_in(beta, c, is32) - mean * g;
    }
    __syncthreads();

    int x0 = blockIdx.x * 32, y = blockIdx.y, b = blockIdx.z;
    for (int e = threadIdx.x; e < 1024; e += 256) {
        int c2 = e & 31, xl = e >> 5;
        unsigned v = *(const unsigned*)&yt2[((b * 96 + y) * 96 + x0 + xl) * 64 + c2 * 2];
        int c = c2 * 2;
        tile[c * 33 + xl]       = lo16(v) * scL[c]     + shL[c];
        tile[(c + 1) * 33 + xl] = hi16(v) * scL[c + 1] + shL[c + 1];
    }
    __syncthreads();
    for (int f = threadIdx.x; f < 2048; f += 256) {
        int xl = f & 31, c = f >> 5;
        int idx = ((b * 64 + c) * 96 + y) * 96 + x0 + xl;
        float v = load_in(xin, idx, is32) + tile[c * 33 + xl];
        if (is32) ((float*)outp)[idx] = v;
        else      ((__hip_bfloat16*)outp)[idx] = __float2bfloat16(v);
    }
}

// ---------------------------------------------------------------------------
extern "C" void kernel_launch(void* const* d_in, const int* in_sizes, int n_in,
                              void* d_out, int out_size, void* d_ws, size_t ws_size,
                              hipStream_t stream) {
    const void* x  = d_in[0];
    const void* w1 = d_in[1];
    const void* g1 = d_in[2];
    const void* b1 = d_in[3];
    const void* w2 = d_in[4];
    const void* g2 = d_in[5];
    const void* b2 = d_in[6];

    __hip_bfloat16* bufA = (__hip_bfloat16*)d_ws;   // xt / yt2 (bf16, aliased)
    __hip_bfloat16* bufB = bufA + NELEM;            // yt1 (bf16)
    __hip_bfloat16* Bfr1 = bufB + NELEM;            // 147456 bf16
    __hip_bfloat16* Bfr2 = Bfr1 + 147456;           // 147456 bf16
    float* statz = (float*)(Bfr2 + 147456);         // 2048 f32
    float* statL1 = statz;
    float* statL2 = statz + 1024;

    prep_kernel<<<721, 256, 0, stream>>>(x, w1, w2, bufA, Bfr1, Bfr2, statz);

    dim3 cgrid(24, 96, 2);   // (xtile of 16 x 4 o-pairs), rows, batch
    caps_kernel<<<cgrid, 256, 0, stream>>>(bufA, nullptr, nullptr, nullptr, w1,
                                           Bfr1, bufB, statL1, 1);
    caps_kernel<<<cgrid, 256, 0, stream>>>(bufB, statL1, g1, b1, w1,
                                           Bfr2, bufA, statL2, 0);
    final_kernel<<<dim3(3, 96, 2), 256, 0, stream>>>(x, bufA, statL2, g2, b2, w1, d_out);
}

// Round 3
// 165.481 us; speedup vs baseline: 1.1306x; 1.0870x over previous
//
#include <hip/hip_runtime.h>
#include <hip/hip_bf16.h>

#define HW 9216          // 96*96
#define NPC 18432        // per-channel element count for BN
#define NELEM 1179648    // 2*64*96*96
#define XSTR 72          // patch x stride (bf16): %8==0, 36dw = +4 banks/pos
#define PATCH_B 7776     // 3*18*72*2 bytes
#define XREC 12          // cross-wave exchange record: 12 f32 = 48 B (16B-aligned)
#define XBUF_B (4*2*16*2*XREC*4)   // 4 slots x o2 x pos x g x rec = 12288 B

typedef __attribute__((ext_vector_type(2))) float f32x2;
typedef __attribute__((ext_vector_type(4))) float f32x4v;
typedef __attribute__((ext_vector_type(8))) short short8v;   // 8 bf16 (4 VGPRs)

__device__ __forceinline__ int detect_is32(const unsigned short* __restrict__ w1u) {
    int lane = threadIdx.x & 63;
    int bad = 0;
    #pragma unroll
    for (int i = 0; i < 16; ++i) {
        unsigned short u = (unsigned short)(w1u[lane + i * 64] & 0x7FFF);
        bad |= (u >= 0x42C8);   // bf16 |v| >= 100 or NaN/Inf
    }
    return (__ballot(bad) != 0ULL) ? 1 : 0;
}

__device__ __forceinline__ float load_in(const void* p, int idx, int is32) {
    return is32 ? ((const float*)p)[idx]
                : __bfloat162float(((const __hip_bfloat16*)p)[idx]);
}

__device__ __forceinline__ float lo16(unsigned v) { return __int_as_float((int)(v << 16)); }
__device__ __forceinline__ float hi16(unsigned v) { return __int_as_float((int)(v & 0xFFFF0000u)); }
__device__ __forceinline__ unsigned pk2bf(float a, float b) {
    __hip_bfloat162 h = __float22bfloat162_rn(float2{a, b});
    return *(unsigned*)&h;
}

// ---------------------------------------------------------------------------
// prep: 0..575 x-transpose to bf16 [b][y][x][c]; 576..719 MFMA B-fragment
// tables; 720 zero BN-stat accumulators.
// ---------------------------------------------------------------------------
__launch_bounds__(256)
__global__ void prep_kernel(const void* __restrict__ x,
                            const void* __restrict__ w1, const void* __restrict__ w2,
                            __hip_bfloat16* __restrict__ xt,
                            __hip_bfloat16* __restrict__ Bfr1,
                            __hip_bfloat16* __restrict__ Bfr2,
                            float* __restrict__ statz) {
    __shared__ float tile[64 * 33];
    const int bid = blockIdx.x;
    if (bid < 576) {
        const int is32 = detect_is32((const unsigned short*)w1);
        int xb = bid % 3, y = (bid / 3) % 96, b = bid / 288;
        int x0 = xb * 32;
        for (int e = threadIdx.x; e < 2048; e += 256) {
            int xl = e & 31, c = e >> 5;
            tile[c * 33 + xl] = load_in(x, ((b * 64 + c) * 96 + y) * 96 + x0 + xl, is32);
        }
        __syncthreads();
        for (int f = threadIdx.x; f < 1024; f += 256) {
            int c2 = f & 31, xl = f >> 5;
            float a = tile[(2 * c2) * 33 + xl];
            float c = tile[(2 * c2 + 1) * 33 + xl];
            *(unsigned*)&xt[((b * 96 + y) * 96 + x0 + xl) * 64 + 2 * c2] = pk2bf(a, c);
        }
    } else if (bid < 720) {
        const int is32 = detect_is32((const unsigned short*)w1);
        int t = (bid - 576) * 256 + threadIdx.x;   // 0..36863
        int layer = t / 18432;
        int r = t - layer * 18432;
        int lane = r & 63;
        int fi = r >> 6;                 // 0..287 = ((o*9+k)*2+g)*2+h
        int h = fi & 1, g = (fi >> 1) & 1;
        int kq = fi >> 2;
        int k = kq % 9, o = kq / 9;
        int dy = k / 3, dx = k % 3;
        int quad = lane >> 4, colhi = (lane >> 3) & 1, m = lane & 7;
        int act = (quad == 2 * h + colhi);
        int i = g * 4 + 2 * h + colhi;
        const void* w = layer ? w2 : w1;
        __hip_bfloat16* dst = layer ? Bfr2 : Bfr1;
        #pragma unroll
        for (int j = 0; j < 8; ++j) {
            float v = act ? load_in(w, ((((o * 8 + i) * 3 + dy) * 3 + dx) * 8 + j) * 8 + m, is32)
                          : 0.f;
            dst[(fi * 64 + lane) * 8 + j] = __float2bfloat16(v);
        }
    } else {
        for (int e = threadIdx.x; e < 2048; e += 256) statz[e] = 0.f;
    }
}

// cross-wave (g) exchange of [4]-float partial + se through a 48B LDS record.
// quads 2,3 hold identical post-xor32 values as 0,1, so only quads 0,1 write.
__device__ __forceinline__ void xexchange(float* __restrict__ xbufF, int slot,
                                          int o2w, int pos16, int g, int quad,
                                          int mhalf, float ac[4], float& se) {
    float* rec = xbufF + ((((slot * 2 + o2w) * 16 + pos16) * 2 + g) * XREC);
    if (quad < 2) {
        *(float4*)(rec + quad * 4) = make_float4(ac[0], ac[1], ac[2], ac[3]);
        if (quad == 0) rec[8] = se;
    }
    __syncthreads();
    const float* prec = xbufF + ((((slot * 2 + o2w) * 16 + pos16) * 2 + (1 - g)) * XREC);
    float4 po = *(const float4*)(prec + mhalf * 4);
    ac[0] += po.x; ac[1] += po.y; ac[2] += po.z; ac[3] += po.w;
    se += prec[8];
}

// ---------------------------------------------------------------------------
// Fused capsule conv (MFMA) + routing + BN-stat partials.  (R19: priors stay
// in REGISTERS — no LDS prior buffer, no bf16 round-trip.)
// Block = 256 threads = 4 waves; tile = 16 x-positions x TWO o.
// Wave wv = (o2w = wv>>1, g = wv&1); lane quad = (ihl = q>>1, mhalf = q&1).
// Phase 1: operand-swapped MFMA, D kept in regs: P[k][h][r] = prior of
//   (i = g*4+2h+ihl, k) for m = mhalf*4+r at column pos16.
// Phase 2: routing directly on P. Unit (pos,o) = 4 quads x 2 g-waves.
//   m-combine = shfl_xor16, ihl-combine = shfl_xor32, g-combine = 48B LDS
//   exchange + barrier (4 total: om-init + 3 iters). Chain ownership
//   h = mhalf: 9 exp-chains per lane, zero duplication. All value selects
//   via cndmask (static array indices — no scratch).
// LDS = patch (7776) + xbuf (12288) ~ 20 KB -> occupancy capped by VGPR at
// 4 waves/SIMD (launch_bounds 256,4; ~110 live VGPRs).
// ---------------------------------------------------------------------------
__launch_bounds__(256, 4)
__global__ void caps_kernel(const __hip_bfloat16* __restrict__ in,  // [b][y][x][64] bf16
                            const float* __restrict__ statPrev,     // BN1 raw stats (layer2)
                            const void* __restrict__ gamma, const void* __restrict__ beta,
                            const void* __restrict__ wdt,           // w1, dtype probe
                            const __hip_bfloat16* __restrict__ Bfr,
                            __hip_bfloat16* __restrict__ yout,      // [b][y][x][64] bf16
                            float* __restrict__ statL,              // [8 copies][128]
                            int layer1) {
    __shared__ __align__(16) unsigned char smem[PATCH_B + XBUF_B];
    __hip_bfloat16* patchH = (__hip_bfloat16*)smem;       // [q=row*18+xo][c] stride XSTR
    float* xbufF = (float*)(smem + PATCH_B);              // exchange slots
    float* omF = (float*)smem;                // 1 KB, aliases patch (dead in epilogue)
    float* scL = (float*)(smem + PATCH_B);    // 256 B, aliases xbuf (staging only)
    float* shL = scL + 64;

    const int gx    = blockIdx.x;    // 0..23
    const int opair = gx & 3;
    const int x0    = (gx >> 2) * 16;
    const int y  = blockIdx.y;
    const int b  = blockIdx.z;
    const int tid = threadIdx.x;

    // ---- inline BN1 params (layer 2 only) ----
    if (!layer1) {
        if (tid < 64) {
            const int is32 = detect_is32((const unsigned short*)wdt);
            int c = tid;
            float s = 0.f, ss = 0.f;
            #pragma unroll
            for (int cp = 0; cp < 8; ++cp) {
                s  += statPrev[cp * 128 + c];
                ss += statPrev[cp * 128 + 64 + c];
            }
            float mean = s * (1.f / (float)NPC);
            float var  = fmaxf(ss * (1.f / (float)NPC) - mean * mean, 0.f);
            float inv  = rsqrtf(var + 1e-5f);
            float g = load_in(gamma, c, is32) * inv;
            scL[c] = g;
            shL[c] = load_in(beta, c, is32) - mean * g;
        }
        __syncthreads();
    }

    // ---- stage patch: rows y-1..y+1, cols x0-1..x0+16, 64 ch bf16 ----
    for (int e = tid; e < 864; e += 256) {
        int c4 = e & 15;             // 4-channel group
        int q  = e >> 4;             // 0..53 = row*18 + xo
        int xo = q % 18, row = q / 18;
        int yy = y + row - 1, xx = x0 + xo - 1;
        uint2 v = {0u, 0u};
        if (yy >= 0 && yy < 96 && xx >= 0 && xx < 96) {
            v = *(const uint2*)&in[((b * 96 + yy) * 96 + xx) * 64 + c4 * 4];
            if (!layer1) {
                int c = c4 * 4;
                float f0 = lo16(v.x) * scL[c]     + shL[c];
                float f1 = hi16(v.x) * scL[c + 1] + shL[c + 1];
                float f2 = lo16(v.y) * scL[c + 2] + shL[c + 2];
                float f3 = hi16(v.y) * scL[c + 3] + shL[c + 3];
                v.x = pk2bf(f0, f1);
                v.y = pk2bf(f2, f3);
            }
        }
        *(uint2*)&patchH[q * XSTR + c4 * 4] = v;
    }
    __syncthreads();      // patch ready; also fences scL reads before xbuf reuse

    const int lane  = tid & 63;
    const int wv    = tid >> 6;      // wave 0..3
    const int o2w   = wv >> 1;       // which o of the pair
    const int g     = wv & 1;        // i-group (MFMA K-slice)
    const int pos16 = lane & 15;     // output position (MFMA B col)
    const int quad  = lane >> 4;
    const int mhalf = quad & 1;      // m-half: m = mhalf*4 + r

    // ================= Phase 1: priors straight into registers ==============
    f32x4v P[9][2];
    {
        const int o = opair * 2 + o2w;
        #pragma unroll
        for (int k = 0; k < 9; ++k) {
            const int dy = k / 3, dx = k % 3;
            short8v a = *(const short8v*)&patchH[(dy * 18 + dx + pos16) * XSTR + g * 32 + quad * 8];
            #pragma unroll
            for (int h = 0; h < 2; ++h) {
                short8v bf = *(const short8v*)&Bfr[((((o * 9 + k) * 2 + g) * 2 + h) * 64 + lane) * 8];
                P[k][h] = __builtin_amdgcn_mfma_f32_16x16x32_bf16(bf, a, (f32x4v){0.f, 0.f, 0.f, 0.f}, 0, 0, 0);
            }
        }
    }

    // ================= Phase 2: routing on register priors ==================
    // n1 for owned cells (h = mhalf), full-m via xor16
    float n1o[9];
    #pragma unroll
    for (int k = 0; k < 9; ++k) {
        float np0 = P[k][0][0] * P[k][0][0];
        np0 = fmaf(P[k][0][1], P[k][0][1], np0);
        np0 = fmaf(P[k][0][2], P[k][0][2], np0);
        np0 = fmaf(P[k][0][3], P[k][0][3], np0);
        float np1 = P[k][1][0] * P[k][1][0];
        np1 = fmaf(P[k][1][1], P[k][1][1], np1);
        np1 = fmaf(P[k][1][2], P[k][1][2], np1);
        np1 = fmaf(P[k][1][3], P[k][1][3], np1);
        float own = mhalf ? np1 : np0;
        float oth = mhalf ? np0 : np1;
        n1o[k] = own + __shfl_xor(oth, 16, 64);
    }

    // om init = mean over all 72 (i,k): in-lane (k,h) + xor32 (ihl) + g-exchange
    float om[4];
    {
        float ac[4];
        #pragma unroll
        for (int r = 0; r < 4; ++r) {
            float s = 0.f;
            #pragma unroll
            for (int k = 0; k < 9; ++k) s += P[k][0][r] + P[k][1][r];
            s += __shfl_xor(s, 32, 64);
            ac[r] = s;
        }
        float dummy = 0.f;
        xexchange(xbufF, 0, o2w, pos16, g, quad, mhalf, ac, dummy);
        #pragma unroll
        for (int r = 0; r < 4; ++r) om[r] = ac[r] * (1.f / 72.f);
    }
    float n2;
    {
        float n2p = om[0] * om[0];
        n2p = fmaf(om[1], om[1], n2p);
        n2p = fmaf(om[2], om[2], n2p);
        n2p = fmaf(om[3], om[3], n2p);
        n2 = n2p + __shfl_xor(n2p, 16, 64);
    }

    #pragma unroll
    for (int it = 0; it < 3; ++it) {
        float se = 0.f;
        float ac[4] = {0.f, 0.f, 0.f, 0.f};
        #pragma unroll
        for (int k = 0; k < 9; ++k) {
            float dp0 = P[k][0][0] * om[0];
            dp0 = fmaf(P[k][0][1], om[1], dp0);
            dp0 = fmaf(P[k][0][2], om[2], dp0);
            dp0 = fmaf(P[k][0][3], om[3], dp0);
            float dp1 = P[k][1][0] * om[0];
            dp1 = fmaf(P[k][1][1], om[1], dp1);
            dp1 = fmaf(P[k][1][2], om[2], dp1);
            dp1 = fmaf(P[k][1][3], om[3], dp1);
            float own = mhalf ? dp1 : dp0;
            float oth = mhalf ? dp0 : dp1;
            float d = own + __shfl_xor(oth, 16, 64);
            float denom = fmaxf(n1o[k] + n2 - d, 1e-8f);
            float e = __expf(d * __builtin_amdgcn_rcpf(denom));
            se += e;
            float e_oth = __shfl_xor(e, 16, 64);
            float eh0 = mhalf ? e_oth : e;
            float eh1 = mhalf ? e : e_oth;
            ac[0] = fmaf(eh0, P[k][0][0], fmaf(eh1, P[k][1][0], ac[0]));
            ac[1] = fmaf(eh0, P[k][0][1], fmaf(eh1, P[k][1][1], ac[1]));
            ac[2] = fmaf(eh0, P[k][0][2], fmaf(eh1, P[k][1][2], ac[2]));
            ac[3] = fmaf(eh0, P[k][0][3], fmaf(eh1, P[k][1][3], ac[3]));
        }
        // reduce: se over xor16+xor32, acc over xor32 (m-halves stay separate)
        se += __shfl_xor(se, 16, 64);
        se += __shfl_xor(se, 32, 64);
        #pragma unroll
        for (int r = 0; r < 4; ++r) ac[r] += __shfl_xor(ac[r], 32, 64);
        xexchange(xbufF, 1 + it, o2w, pos16, g, quad, mhalf, ac, se);
        float inv = __builtin_amdgcn_rcpf(se);
        #pragma unroll
        for (int r = 0; r < 4; ++r) om[r] = ac[r] * inv;
        float n2p = om[0] * om[0];
        n2p = fmaf(om[1], om[1], n2p);
        n2p = fmaf(om[2], om[2], n2p);
        n2p = fmaf(om[3], om[3], n2p);
        n2 = n2p + __shfl_xor(n2p, 16, 64);
    }

    // ---- output + park f32 finals for BN stats (patch region, now dead) ----
    if (g == 0 && quad < 2) {
        const int o = opair * 2 + o2w;
        uint2 pk;
        pk.x = pk2bf(om[0], om[1]);
        pk.y = pk2bf(om[2], om[3]);
        *(uint2*)&yout[((b * 96 + y) * 96 + x0 + pos16) * 64 + o * 8 + mhalf * 4] = pk;
        *(float4*)&omF[(o2w * 16 + pos16) * 8 + mhalf * 4] = make_float4(om[0], om[1], om[2], om[3]);
    }
    __syncthreads();

    // ---- BN stat partials: this block's 16 channels, sum over 16 positions ----
    if (tid < 32) {
        int c16 = tid & 15, sel = tid >> 4;
        int oo2 = c16 >> 3, m = c16 & 7;
        float v = 0.f;
        #pragma unroll
        for (int pp = 0; pp < 16; ++pp) {
            float t = omF[(oo2 * 16 + pp) * 8 + m];
            v += sel ? t * t : t;
        }
        int cp = (blockIdx.x + blockIdx.y * 3 + blockIdx.z) & 7;
        atomicAdd(&statL[cp * 128 + sel * 64 + (opair * 2 + oo2) * 8 + m], v);
    }
}

// ---------------------------------------------------------------------------
// Final: out[b][c][y][x] = x + bn2(y2); bn2 params computed inline per block.
// ---------------------------------------------------------------------------
__launch_bounds__(256)
__global__ void final_kernel(const void* __restrict__ xin,
                             const __hip_bfloat16* __restrict__ yt2,
                             const float* __restrict__ statL,
                             const void* __restrict__ gamma, const void* __restrict__ beta,
                             const void* __restrict__ w1,
                             void* __restrict__ outp) {
    __shared__ float tile[64 * 33];
    __shared__ float scL[64], shL[64];
    const int is32 = detect_is32((const unsigned short*)w1);
    if (threadIdx.x < 64) {
        int c = threadIdx.x;
        float s = 0.f, ss = 0.f;
        #pragma unroll
        for (int cp = 0; cp < 8; ++cp) {
            s  += statL[cp * 128 + c];
            ss += statL[cp * 128 + 64 + c];
        }
        float mean = s * (1.f / (float)NPC);
        float var  = fmaxf(ss * (1.f / (float)NPC) - mean * mean, 0.f);
        float inv  = rsqrtf(var + 1e-5f);
        float g = load_in(gamma, c, is32) * inv;
        scL[c] = g;
        shL[c] = load_in(beta, c, is32) - mean * g;
    }
    __syncthreads();

    int x0 = blockIdx.x * 32, y = blockIdx.y, b = blockIdx.z;
    for (int e = threadIdx.x; e < 1024; e += 256) {
        int c2 = e & 31, xl = e >> 5;
        unsigned v = *(const unsigned*)&yt2[((b * 96 + y) * 96 + x0 + xl) * 64 + c2 * 2];
        int c = c2 * 2;
        tile[c * 33 + xl]       = lo16(v) * scL[c]     + shL[c];
        tile[(c + 1) * 33 + xl] = hi16(v) * scL[c + 1] + shL[c + 1];
    }
    __syncthreads();
    for (int f = threadIdx.x; f < 2048; f += 256) {
        int xl = f & 31, c = f >> 5;
        int idx = ((b * 64 + c) * 96 + y) * 96 + x0 + xl;
        float v = load_in(xin, idx, is32) + tile[c * 33 + xl];
        if (is32) ((float*)outp)[idx] = v;
        else      ((__hip_bfloat16*)outp)[idx] = __float2bfloat16(v);
    }
}

// ---------------------------------------------------------------------------
extern "C" void kernel_launch(void* const* d_in, const int* in_sizes, int n_in,
                              void* d_out, int out_size, void* d_ws, size_t ws_size,
                              hipStream_t stream) {
    const void* x  = d_in[0];
    const void* w1 = d_in[1];
    const void* g1 = d_in[2];
    const void* b1 = d_in[3];
    const void* w2 = d_in[4];
    const void* g2 = d_in[5];
    const void* b2 = d_in[6];

    __hip_bfloat16* bufA = (__hip_bfloat16*)d_ws;   // xt / yt2 (bf16, aliased)
    __hip_bfloat16* bufB = bufA + NELEM;            // yt1 (bf16)
    __hip_bfloat16* Bfr1 = bufB + NELEM;            // 147456 bf16
    __hip_bfloat16* Bfr2 = Bfr1 + 147456;           // 147456 bf16
    float* statz = (float*)(Bfr2 + 147456);         // 2048 f32
    float* statL1 = statz;
    float* statL2 = statz + 1024;

    prep_kernel<<<721, 256, 0, stream>>>(x, w1, w2, bufA, Bfr1, Bfr2, statz);

    dim3 cgrid(24, 96, 2);   // (xtile of 16 x 4 o-pairs), rows, batch
    caps_kernel<<<cgrid, 256, 0, stream>>>(bufA, nullptr, nullptr, nullptr, w1,
                                           Bfr1, bufB, statL1, 1);
    caps_kernel<<<cgrid, 256, 0, stream>>>(bufB, statL1, g1, b1, w1,
                                           Bfr2, bufA, statL2, 0);
    final_kernel<<<dim3(3, 96, 2), 256, 0, stream>>>(x, bufA, statL2, g2, b2, w1, d_out);
}